// Round 1
// baseline (930.000 us; speedup 1.0000x reference)
//
#include <hip/hip_runtime.h>
#include <math.h>

#define NEG_SLOPE 0.2f
#define LN_EPS 1e-5f

__device__ __forceinline__ int enc_f(float f) {
    int i = __float_as_int(f);
    return (i >= 0) ? i : (i ^ 0x7FFFFFFF);
}
__device__ __forceinline__ float dec_f(int i) {
    return __int_as_float((i >= 0) ? i : (i ^ 0x7FFFFFFF));
}

// init amax to encode(-inf), den to 0
__global__ void init_kernel(int* __restrict__ amax, float* __restrict__ den, int n4) {
    int i = blockIdx.x * blockDim.x + threadIdx.x;
    if (i < n4) { amax[i] = 0x807FFFFF; den[i] = 0.0f; }
}

// xl = x@W_l + b_l ; xr = x@W_r + b_r   (64->64 each). 4 rows per block-iter.
__global__ __launch_bounds__(256) void node_xf(
    const float* __restrict__ x,
    const float* __restrict__ W_l, const float* __restrict__ b_l,
    const float* __restrict__ W_r, const float* __restrict__ b_r,
    float* __restrict__ xl, float* __restrict__ xr, int n) {
    __shared__ float sWl[64 * 64];
    __shared__ float sWr[64 * 64];
    __shared__ float sx[4 * 64];
    for (int i = threadIdx.x; i < 4096; i += 256) { sWl[i] = W_l[i]; sWr[i] = W_r[i]; }
    __syncthreads();
    int lane = threadIdx.x & 63;
    int w = threadIdx.x >> 6;
    float bl = b_l[lane], br = b_r[lane];
    for (int base = blockIdx.x * 4; base < n; base += gridDim.x * 4) {
        __syncthreads();
        int r = base + w;
        if (r < n) sx[threadIdx.x] = x[(size_t)r * 64 + lane];
        __syncthreads();
        if (r < n) {
            float al = bl, ar = br;
            const float* xv = &sx[w * 64];
#pragma unroll
            for (int k = 0; k < 64; ++k) {
                float xk = xv[k];
                al = fmaf(xk, sWl[k * 64 + lane], al);
                ar = fmaf(xk, sWr[k * 64 + lane], ar);
            }
            xl[(size_t)r * 64 + lane] = al;
            xr[(size_t)r * 64 + lane] = ar;
        }
    }
}

// one wave per edge: compute logits[e,h], atomicMax into amax[dst,h]
__global__ __launch_bounds__(256) void edge_logits(
    const int* __restrict__ ei, const float* __restrict__ eattr,
    const int* __restrict__ dist, const float* __restrict__ bph,
    const float* __restrict__ W_e, const float* __restrict__ att,
    const float* __restrict__ xl, const float* __restrict__ xr,
    float* __restrict__ logits, int* __restrict__ amax, int E_) {
    __shared__ float sWe[16 * 64];
    for (int i = threadIdx.x; i < 1024; i += 256) sWe[i] = W_e[i];
    __syncthreads();
    int lane = threadIdx.x & 63;
    int h = lane >> 4;
    float attv = att[lane];
    int wid = (blockIdx.x * blockDim.x + threadIdx.x) >> 6;
    int nw = (gridDim.x * blockDim.x) >> 6;
    for (int e = wid; e < E_; e += nw) {
        int src = ei[e];
        int dst = ei[E_ + e];
        int hop = dist[dst];
        hop = hop < 0 ? 0 : (hop > 3 ? 3 : hop);
        float hb = 0.1f * bph[hop];
        float m = xl[(size_t)src * 64 + lane] + xr[(size_t)dst * 64 + lane];
        const float* ea = &eattr[(size_t)e * 16];
#pragma unroll
        for (int k = 0; k < 16; ++k)
            m = fmaf(ea[k] + hb, sWe[k * 64 + lane], m);
        m = m > 0.0f ? m : NEG_SLOPE * m;
        float l = m * attv;
#pragma unroll
        for (int off = 1; off < 16; off <<= 1) l += __shfl_xor(l, off, 64);
        if ((lane & 15) == 0) {
            logits[(size_t)e * 4 + h] = l;
            atomicMax(&amax[dst * 4 + h], enc_f(l));
        }
    }
}

// one wave per edge: ex = exp(l - amax[dst]); den[dst,h]+=ex; out[dst,:]+=ex*xl[src,:]
__global__ __launch_bounds__(256) void edge_scatter(
    const int* __restrict__ ei, const float* __restrict__ logits,
    const int* __restrict__ amax, const float* __restrict__ xl,
    float* __restrict__ den, float* __restrict__ out, int E_) {
    int lane = threadIdx.x & 63;
    int h = lane >> 4;
    int wid = (blockIdx.x * blockDim.x + threadIdx.x) >> 6;
    int nw = (gridDim.x * blockDim.x) >> 6;
    for (int e = wid; e < E_; e += nw) {
        int src = ei[e];
        int dst = ei[E_ + e];
        float l = logits[(size_t)e * 4 + h];
        float mx = dec_f(amax[dst * 4 + h]);
        float ex = __expf(l - mx);
        if ((lane & 15) == 0) atomicAdd(&den[dst * 4 + h], ex);
        atomicAdd(&out[(size_t)dst * 64 + lane], ex * xl[(size_t)src * 64 + lane]);
    }
}

// out = LN(acc/den + bias)*gamma+beta + x@W_res + b_res
__global__ __launch_bounds__(256) void finalize(
    const float* __restrict__ x, const float* __restrict__ W_res,
    const float* __restrict__ b_res, const float* __restrict__ bias,
    const float* __restrict__ gamma, const float* __restrict__ beta,
    const float* __restrict__ den, float* __restrict__ out, int n) {
    __shared__ float sW[64 * 64];
    __shared__ float sx[4 * 64];
    for (int i = threadIdx.x; i < 4096; i += 256) sW[i] = W_res[i];
    __syncthreads();
    int lane = threadIdx.x & 63;
    int w = threadIdx.x >> 6;
    float bi = bias[lane], g = gamma[lane], be = beta[lane], brs = b_res[lane];
    for (int base = blockIdx.x * 4; base < n; base += gridDim.x * 4) {
        __syncthreads();
        int r = base + w;
        if (r < n) sx[threadIdx.x] = x[(size_t)r * 64 + lane];
        __syncthreads();
        if (r < n) {
            float v = out[(size_t)r * 64 + lane] / (den[r * 4 + (lane >> 4)] + 1e-16f) + bi;
            float s = v;
#pragma unroll
            for (int off = 1; off < 64; off <<= 1) s += __shfl_xor(s, off, 64);
            float mu = s * (1.0f / 64.0f);
            float d = v - mu;
            float q = d * d;
#pragma unroll
            for (int off = 1; off < 64; off <<= 1) q += __shfl_xor(q, off, 64);
            float var = q * (1.0f / 64.0f);
            float nv = d * rsqrtf(var + LN_EPS) * g + be;
            float rres = brs;
            const float* xv = &sx[w * 64];
#pragma unroll
            for (int k = 0; k < 64; ++k) rres = fmaf(xv[k], sW[k * 64 + lane], rres);
            out[(size_t)r * 64 + lane] = nv + rres;
        }
    }
}

extern "C" void kernel_launch(void* const* d_in, const int* in_sizes, int n_in,
                              void* d_out, int out_size, void* d_ws, size_t ws_size,
                              hipStream_t stream) {
    const float* x     = (const float*)d_in[0];
    const int*   ei    = (const int*)d_in[1];
    const float* eattr = (const float*)d_in[2];
    const int*   dist  = (const int*)d_in[3];
    const float* W_l   = (const float*)d_in[4];
    const float* b_l   = (const float*)d_in[5];
    const float* W_r   = (const float*)d_in[6];
    const float* b_r   = (const float*)d_in[7];
    const float* W_e   = (const float*)d_in[8];
    const float* att   = (const float*)d_in[9];
    const float* bias  = (const float*)d_in[10];
    const float* gamma = (const float*)d_in[11];
    const float* beta  = (const float*)d_in[12];
    const float* W_res = (const float*)d_in[13];
    const float* b_res = (const float*)d_in[14];
    const float* bph   = (const float*)d_in[15];

    int n  = in_sizes[0] / 64;
    int E_ = in_sizes[1] / 2;
    float* out = (float*)d_out;

    char* ws = (char*)d_ws;
    float* xl     = (float*)ws; ws += (size_t)n * 64 * 4;
    float* xr     = (float*)ws; ws += (size_t)n * 64 * 4;
    float* logits = (float*)ws; ws += (size_t)E_ * 4 * 4;
    int*   amax   = (int*)ws;   ws += (size_t)n * 4 * 4;
    float* den    = (float*)ws; ws += (size_t)n * 4 * 4;

    hipMemsetAsync(out, 0, (size_t)n * 64 * 4, stream);
    init_kernel<<<(n * 4 + 255) / 256, 256, 0, stream>>>(amax, den, n * 4);
    node_xf<<<2048, 256, 0, stream>>>(x, W_l, b_l, W_r, b_r, xl, xr, n);
    edge_logits<<<2048, 256, 0, stream>>>(ei, eattr, dist, bph, W_e, att, xl, xr, logits, amax, E_);
    edge_scatter<<<2048, 256, 0, stream>>>(ei, logits, amax, xl, den, out, E_);
    finalize<<<2048, 256, 0, stream>>>(x, W_res, b_res, bias, gamma, beta, den, out, n);
}

// Round 2
// 823.692 us; speedup vs baseline: 1.1291x; 1.1291x over previous
//
#include <hip/hip_runtime.h>
#include <math.h>

#define NEG_SLOPE 0.2f
#define LN_EPS 1e-5f
#define NEG_INF (-1e30f)

// ---------- node transform: xl = x@W_l+b_l ; xr = x@W_r+b_r ----------
__global__ __launch_bounds__(256) void node_xf(
    const float* __restrict__ x,
    const float* __restrict__ W_l, const float* __restrict__ b_l,
    const float* __restrict__ W_r, const float* __restrict__ b_r,
    float* __restrict__ xl, float* __restrict__ xr, int n) {
    __shared__ float sWl[64 * 64];
    __shared__ float sWr[64 * 64];
    __shared__ float sx[4 * 64];
    for (int i = threadIdx.x; i < 4096; i += 256) { sWl[i] = W_l[i]; sWr[i] = W_r[i]; }
    __syncthreads();
    int lane = threadIdx.x & 63;
    int w = threadIdx.x >> 6;
    float bl = b_l[lane], br = b_r[lane];
    for (int base = blockIdx.x * 4; base < n; base += gridDim.x * 4) {
        __syncthreads();
        int r = base + w;
        if (r < n) sx[threadIdx.x] = x[(size_t)r * 64 + lane];
        __syncthreads();
        if (r < n) {
            float al = bl, ar = br;
            const float* xv = &sx[w * 64];
#pragma unroll
            for (int k = 0; k < 64; ++k) {
                float xk = xv[k];
                al = fmaf(xk, sWl[k * 64 + lane], al);
                ar = fmaf(xk, sWr[k * 64 + lane], ar);
            }
            xl[(size_t)r * 64 + lane] = al;
            xr[(size_t)r * 64 + lane] = ar;
        }
    }
}

// ---------- histogram: counts[dst]++, pos[e] = old count ----------
__global__ void hist_kernel(const int* __restrict__ ei, int* __restrict__ counts,
                            int* __restrict__ pos, int E_) {
    int e = blockIdx.x * blockDim.x + threadIdx.x;
    if (e < E_) {
        int dst = ei[E_ + e];
        pos[e] = atomicAdd(&counts[dst], 1);
    }
}

// ---------- exclusive scan of counts -> starts (chunked) ----------
#define SCAN_CHUNK 1024
__global__ __launch_bounds__(256) void scan1(const int* __restrict__ counts,
                                             int* __restrict__ starts,
                                             int* __restrict__ partials, int n) {
    __shared__ int wsum[4];
    int base = blockIdx.x * SCAN_CHUNK;
    int t = threadIdx.x;
    int v[4]; int s = 0;
#pragma unroll
    for (int k = 0; k < 4; ++k) {
        int i = base + t * 4 + k;
        v[k] = (i < n) ? counts[i] : 0;
        s += v[k];
    }
    int lane = t & 63, w = t >> 6;
    int inc = s;
#pragma unroll
    for (int off = 1; off < 64; off <<= 1) {
        int u = __shfl_up(inc, off, 64);
        if (lane >= off) inc += u;
    }
    if (lane == 63) wsum[w] = inc;
    __syncthreads();
    int woff = 0;
    for (int i = 0; i < w; ++i) woff += wsum[i];
    int exc = woff + inc - s;
#pragma unroll
    for (int k = 0; k < 4; ++k) {
        int i = base + t * 4 + k;
        if (i < n) starts[i] = exc;
        exc += v[k];
    }
    if (t == 255) partials[blockIdx.x] = woff + inc;
}

__global__ __launch_bounds__(1024) void scan2(int* __restrict__ partials, int nchunks) {
    __shared__ int wsum[16];
    int t = threadIdx.x;
    int v = (t < nchunks) ? partials[t] : 0;
    int lane = t & 63, w = t >> 6;
    int inc = v;
#pragma unroll
    for (int off = 1; off < 64; off <<= 1) {
        int u = __shfl_up(inc, off, 64);
        if (lane >= off) inc += u;
    }
    if (lane == 63) wsum[w] = inc;
    __syncthreads();
    int woff = 0;
    for (int i = 0; i < w; ++i) woff += wsum[i];
    if (t < nchunks) partials[t] = woff + inc - v;
}

__global__ void scan3(int* __restrict__ starts, const int* __restrict__ partials, int n) {
    int i = blockIdx.x * blockDim.x + threadIdx.x;
    if (i < n) starts[i] += partials[i >> 10];
}

// ---------- edge logits -> CSR slots ----------
__global__ __launch_bounds__(256) void edge_logits(
    const int* __restrict__ ei, const float* __restrict__ eattr,
    const int* __restrict__ dist, const float* __restrict__ bph,
    const float* __restrict__ W_e, const float* __restrict__ att,
    const float* __restrict__ xl, const float* __restrict__ xr,
    const int* __restrict__ starts, const int* __restrict__ pos,
    float* __restrict__ logits_csr, int* __restrict__ src_csr, int E_) {
    __shared__ float sWe[16 * 64];
    for (int i = threadIdx.x; i < 1024; i += 256) sWe[i] = W_e[i];
    __syncthreads();
    int lane = threadIdx.x & 63;
    int h = lane >> 4;
    float attv = att[lane];
    int wid = (blockIdx.x * blockDim.x + threadIdx.x) >> 6;
    int nw = (gridDim.x * blockDim.x) >> 6;
    for (int e = wid; e < E_; e += nw) {
        int src = ei[e];
        int dst = ei[E_ + e];
        int hop = dist[dst];
        hop = hop < 0 ? 0 : (hop > 3 ? 3 : hop);
        float hb = 0.1f * bph[hop];
        float m = xl[(size_t)src * 64 + lane] + xr[(size_t)dst * 64 + lane];
        const float* ea = &eattr[(size_t)e * 16];
#pragma unroll
        for (int k = 0; k < 16; ++k)
            m = fmaf(ea[k] + hb, sWe[k * 64 + lane], m);
        m = m > 0.0f ? m : NEG_SLOPE * m;
        float l = m * attv;
#pragma unroll
        for (int off = 1; off < 16; off <<= 1) l += __shfl_xor(l, off, 64);
        int idx = starts[dst] + pos[e];
        if ((lane & 15) == 0) {
            logits_csr[(size_t)idx * 4 + h] = l;
        }
        if (lane == 0) src_csr[idx] = src;
    }
}

// ---------- gather + softmax + LN + residual, one wave per dst node ----------
__global__ __launch_bounds__(256) void gather_finalize(
    const int* __restrict__ starts, const int* __restrict__ counts,
    const float* __restrict__ logits_csr, const int* __restrict__ src_csr,
    const float* __restrict__ xl, const float* __restrict__ x,
    const float* __restrict__ W_res, const float* __restrict__ b_res,
    const float* __restrict__ bias, const float* __restrict__ gamma,
    const float* __restrict__ beta, float* __restrict__ out, int n) {
    __shared__ float sW[64 * 64];
    for (int i = threadIdx.x; i < 4096; i += 256) sW[i] = W_res[i];
    __syncthreads();
    int lane = threadIdx.x & 63;
    float bi = bias[lane], g = gamma[lane], be = beta[lane], brs = b_res[lane];
    int wid = (blockIdx.x * blockDim.x + threadIdx.x) >> 6;
    int nw = (gridDim.x * blockDim.x) >> 6;
    for (int r = wid; r < n; r += nw) {
        int s0 = starts[r];
        int cnt = counts[r];
        // sweep 1: per-head max (lane reads slot lane>>2, head lane&3)
        float mv = NEG_INF;
        for (int b = 0; b < cnt; b += 16) {
            int i = b + (lane >> 2);
            float lg = (i < cnt) ? logits_csr[(size_t)(s0 + i) * 4 + (lane & 3)] : NEG_INF;
            mv = fmaxf(mv, lg);
        }
#pragma unroll
        for (int off = 4; off < 64; off <<= 1) mv = fmaxf(mv, __shfl_xor(mv, off, 64));
        float mx = __shfl(mv, lane >> 4, 64);  // max of head (lane>>4)
        // sweep 2: accumulate
        float acc = 0.0f, den = 0.0f;
        for (int i = 0; i < cnt; ++i) {
            int slot = s0 + i;
            int src = src_csr[slot];
            float l = logits_csr[(size_t)slot * 4 + (lane >> 4)];
            float ex = __expf(l - mx);
            den += ex;
            acc = fmaf(ex, xl[(size_t)src * 64 + lane], acc);
        }
        float v = acc / (den + 1e-16f) + bi;
        // LayerNorm over 64 features
        float s = v;
#pragma unroll
        for (int off = 1; off < 64; off <<= 1) s += __shfl_xor(s, off, 64);
        float mu = s * (1.0f / 64.0f);
        float d = v - mu;
        float q = d * d;
#pragma unroll
        for (int off = 1; off < 64; off <<= 1) q += __shfl_xor(q, off, 64);
        float var = q * (1.0f / 64.0f);
        float nv = d * rsqrtf(var + LN_EPS) * g + be;
        // residual GEMV: x[r] @ W_res + b_res
        float xv = x[(size_t)r * 64 + lane];
        float rres = brs;
#pragma unroll
        for (int k = 0; k < 64; ++k) rres = fmaf(__shfl(xv, k, 64), sW[k * 64 + lane], rres);
        out[(size_t)r * 64 + lane] = nv + rres;
    }
}

extern "C" void kernel_launch(void* const* d_in, const int* in_sizes, int n_in,
                              void* d_out, int out_size, void* d_ws, size_t ws_size,
                              hipStream_t stream) {
    const float* x     = (const float*)d_in[0];
    const int*   ei    = (const int*)d_in[1];
    const float* eattr = (const float*)d_in[2];
    const int*   dist  = (const int*)d_in[3];
    const float* W_l   = (const float*)d_in[4];
    const float* b_l   = (const float*)d_in[5];
    const float* W_r   = (const float*)d_in[6];
    const float* b_r   = (const float*)d_in[7];
    const float* W_e   = (const float*)d_in[8];
    const float* att   = (const float*)d_in[9];
    const float* bias  = (const float*)d_in[10];
    const float* gamma = (const float*)d_in[11];
    const float* beta  = (const float*)d_in[12];
    const float* W_res = (const float*)d_in[13];
    const float* b_res = (const float*)d_in[14];
    const float* bph   = (const float*)d_in[15];

    int n  = in_sizes[0] / 64;
    int E_ = in_sizes[1] / 2;
    float* out = (float*)d_out;

    char* ws = (char*)d_ws;
    float* xl         = (float*)ws; ws += (size_t)n * 64 * 4;
    float* xr         = (float*)ws; ws += (size_t)n * 64 * 4;
    float* logits_csr = (float*)ws; ws += (size_t)E_ * 4 * 4;
    int*   src_csr    = (int*)ws;   ws += (size_t)E_ * 4;
    int*   pos        = (int*)ws;   ws += (size_t)E_ * 4;
    int*   counts     = (int*)ws;   ws += (size_t)n * 4;
    int*   starts     = (int*)ws;   ws += (size_t)n * 4;
    int*   partials   = (int*)ws;   ws += (size_t)1024 * 4;

    int nchunks = (n + SCAN_CHUNK - 1) / SCAN_CHUNK;

    hipMemsetAsync(counts, 0, (size_t)n * 4, stream);
    node_xf<<<2048, 256, 0, stream>>>(x, W_l, b_l, W_r, b_r, xl, xr, n);
    hist_kernel<<<(E_ + 255) / 256, 256, 0, stream>>>(ei, counts, pos, E_);
    scan1<<<nchunks, 256, 0, stream>>>(counts, starts, partials, n);
    scan2<<<1, 1024, 0, stream>>>(partials, nchunks);
    scan3<<<(n + 255) / 256, 256, 0, stream>>>(starts, partials, n);
    edge_logits<<<2048, 256, 0, stream>>>(ei, eattr, dist, bph, W_e, att, xl, xr,
                                          starts, pos, logits_csr, src_csr, E_);
    gather_finalize<<<2048, 256, 0, stream>>>(starts, counts, logits_csr, src_csr,
                                              xl, x, W_res, b_res, bias, gamma, beta, out, n);
}

// Round 3
// 633.925 us; speedup vs baseline: 1.4670x; 1.2994x over previous
//
#include <hip/hip_runtime.h>
#include <math.h>

#define NEG_SLOPE 0.2f
#define LN_EPS 1e-5f
#define NEG_INF (-1e30f)

// ---------- node transform: xl = x@W_l+b_l ; xr = x@W_r+b_r ----------
__global__ __launch_bounds__(256) void node_xf(
    const float* __restrict__ x,
    const float* __restrict__ W_l, const float* __restrict__ b_l,
    const float* __restrict__ W_r, const float* __restrict__ b_r,
    float* __restrict__ xl, float* __restrict__ xr, int n) {
    __shared__ float sWl[64 * 64];
    __shared__ float sWr[64 * 64];
    __shared__ float sx[4 * 64];
    for (int i = threadIdx.x; i < 4096; i += 256) { sWl[i] = W_l[i]; sWr[i] = W_r[i]; }
    __syncthreads();
    int lane = threadIdx.x & 63;
    int w = threadIdx.x >> 6;
    float bl = b_l[lane], br = b_r[lane];
    for (int base = blockIdx.x * 4; base < n; base += gridDim.x * 4) {
        __syncthreads();
        int r = base + w;
        if (r < n) sx[threadIdx.x] = x[(size_t)r * 64 + lane];
        __syncthreads();
        if (r < n) {
            float al = bl, ar = br;
            const float* xv = &sx[w * 64];
#pragma unroll
            for (int k = 0; k < 64; ++k) {
                float xk = xv[k];
                al = fmaf(xk, sWl[k * 64 + lane], al);
                ar = fmaf(xk, sWr[k * 64 + lane], ar);
            }
            xl[(size_t)r * 64 + lane] = al;
            xr[(size_t)r * 64 + lane] = ar;
        }
    }
}

// ---------- histogram: counts[dst]++, pos[e] = old count ----------
__global__ void hist_kernel(const int* __restrict__ ei, int* __restrict__ counts,
                            int* __restrict__ pos, int E_) {
    int e = blockIdx.x * blockDim.x + threadIdx.x;
    if (e < E_) {
        int dst = ei[E_ + e];
        pos[e] = atomicAdd(&counts[dst], 1);
    }
}

// ---------- exclusive scan of counts -> starts (chunked) ----------
#define SCAN_CHUNK 1024
__global__ __launch_bounds__(256) void scan1(const int* __restrict__ counts,
                                             int* __restrict__ starts,
                                             int* __restrict__ partials, int n) {
    __shared__ int wsum[4];
    int base = blockIdx.x * SCAN_CHUNK;
    int t = threadIdx.x;
    int v[4]; int s = 0;
#pragma unroll
    for (int k = 0; k < 4; ++k) {
        int i = base + t * 4 + k;
        v[k] = (i < n) ? counts[i] : 0;
        s += v[k];
    }
    int lane = t & 63, w = t >> 6;
    int inc = s;
#pragma unroll
    for (int off = 1; off < 64; off <<= 1) {
        int u = __shfl_up(inc, off, 64);
        if (lane >= off) inc += u;
    }
    if (lane == 63) wsum[w] = inc;
    __syncthreads();
    int woff = 0;
    for (int i = 0; i < w; ++i) woff += wsum[i];
    int exc = woff + inc - s;
#pragma unroll
    for (int k = 0; k < 4; ++k) {
        int i = base + t * 4 + k;
        if (i < n) starts[i] = exc;
        exc += v[k];
    }
    if (t == 255) partials[blockIdx.x] = woff + inc;
}

__global__ __launch_bounds__(1024) void scan2(int* __restrict__ partials, int nchunks) {
    __shared__ int wsum[16];
    int t = threadIdx.x;
    int v = (t < nchunks) ? partials[t] : 0;
    int lane = t & 63, w = t >> 6;
    int inc = v;
#pragma unroll
    for (int off = 1; off < 64; off <<= 1) {
        int u = __shfl_up(inc, off, 64);
        if (lane >= off) inc += u;
    }
    if (lane == 63) wsum[w] = inc;
    __syncthreads();
    int woff = 0;
    for (int i = 0; i < w; ++i) woff += wsum[i];
    if (t < nchunks) partials[t] = woff + inc - v;
}

__global__ void scan3(int* __restrict__ starts, const int* __restrict__ partials, int n) {
    int i = blockIdx.x * blockDim.x + threadIdx.x;
    if (i < n) starts[i] += partials[i >> 10];
}

// ---------- place: es[slot] = (e, src) ----------
__global__ void place_kernel(const int* __restrict__ ei, const int* __restrict__ starts,
                             const int* __restrict__ pos, int2* __restrict__ es, int E_) {
    int e = blockIdx.x * blockDim.x + threadIdx.x;
    if (e < E_) {
        int dst = ei[E_ + e];
        int idx = starts[dst] + pos[e];
        es[idx] = make_int2(e, ei[e]);
    }
}

// ---------- fused: edge logits + online softmax + gather + LN + residual ----------
// one wave per dst node
__global__ __launch_bounds__(256) void fused_gather(
    const int* __restrict__ starts, const int* __restrict__ counts,
    const int2* __restrict__ es, const float* __restrict__ eattr,
    const int* __restrict__ dist, const float* __restrict__ bph,
    const float* __restrict__ W_e, const float* __restrict__ att,
    const float* __restrict__ xl, const float* __restrict__ xr,
    const float* __restrict__ x, const float* __restrict__ W_res,
    const float* __restrict__ b_res, const float* __restrict__ bias,
    const float* __restrict__ gamma, const float* __restrict__ beta,
    float* __restrict__ out, int n) {
    __shared__ float sW[64 * 64];
    __shared__ float sWe[16 * 64];
    for (int i = threadIdx.x; i < 4096; i += 256) sW[i] = W_res[i];
    for (int i = threadIdx.x; i < 1024; i += 256) sWe[i] = W_e[i];
    __syncthreads();
    int lane = threadIdx.x & 63;
    float attv = att[lane];
    float bi = bias[lane], g = gamma[lane], be = beta[lane], brs = b_res[lane];
    int wid = (blockIdx.x * blockDim.x + threadIdx.x) >> 6;
    int nw = (gridDim.x * blockDim.x) >> 6;
    for (int r = wid; r < n; r += nw) {
        int s0 = starts[r];
        int cnt = counts[r];
        float xrv = xr[(size_t)r * 64 + lane];
        int hop = dist[r];
        hop = hop < 0 ? 0 : (hop > 3 ? 3 : hop);
        float hb = 0.1f * bph[hop];

        float mrun = NEG_INF, den = 0.0f, acc = 0.0f;
        int2 nxt;
        if (cnt > 0) nxt = es[s0];
        for (int i = 0; i < cnt; ++i) {
            int2 cur = nxt;
            if (i + 1 < cnt) nxt = es[s0 + i + 1];
            float xlv = xl[(size_t)cur.y * 64 + lane];
            const float4* ea = (const float4*)(eattr + (size_t)cur.x * 16);
            float4 e0 = ea[0], e1 = ea[1], e2 = ea[2], e3 = ea[3];
            float m = xlv + xrv;
            m = fmaf(e0.x + hb, sWe[0 * 64 + lane], m);
            m = fmaf(e0.y + hb, sWe[1 * 64 + lane], m);
            m = fmaf(e0.z + hb, sWe[2 * 64 + lane], m);
            m = fmaf(e0.w + hb, sWe[3 * 64 + lane], m);
            m = fmaf(e1.x + hb, sWe[4 * 64 + lane], m);
            m = fmaf(e1.y + hb, sWe[5 * 64 + lane], m);
            m = fmaf(e1.z + hb, sWe[6 * 64 + lane], m);
            m = fmaf(e1.w + hb, sWe[7 * 64 + lane], m);
            m = fmaf(e2.x + hb, sWe[8 * 64 + lane], m);
            m = fmaf(e2.y + hb, sWe[9 * 64 + lane], m);
            m = fmaf(e2.z + hb, sWe[10 * 64 + lane], m);
            m = fmaf(e2.w + hb, sWe[11 * 64 + lane], m);
            m = fmaf(e3.x + hb, sWe[12 * 64 + lane], m);
            m = fmaf(e3.y + hb, sWe[13 * 64 + lane], m);
            m = fmaf(e3.z + hb, sWe[14 * 64 + lane], m);
            m = fmaf(e3.w + hb, sWe[15 * 64 + lane], m);
            m = m > 0.0f ? m : NEG_SLOPE * m;
            float l = m * attv;
#pragma unroll
            for (int off = 1; off < 16; off <<= 1) l += __shfl_xor(l, off, 64);
            // online softmax update (per-head, replicated across 16 lanes)
            float mnew = fmaxf(mrun, l);
            float corr = __expf(mrun - mnew);
            float ex = __expf(l - mnew);
            den = den * corr + ex;
            acc = fmaf(ex, xlv, acc * corr);
            mrun = mnew;
        }
        float v = acc / (den + 1e-16f) + bi;
        // LayerNorm over 64 features
        float s = v;
#pragma unroll
        for (int off = 1; off < 64; off <<= 1) s += __shfl_xor(s, off, 64);
        float mu = s * (1.0f / 64.0f);
        float d = v - mu;
        float q = d * d;
#pragma unroll
        for (int off = 1; off < 64; off <<= 1) q += __shfl_xor(q, off, 64);
        float var = q * (1.0f / 64.0f);
        float nv = d * rsqrtf(var + LN_EPS) * g + be;
        // residual GEMV: x[r] @ W_res + b_res
        float xv = x[(size_t)r * 64 + lane];
        float rres = brs;
#pragma unroll
        for (int k = 0; k < 64; ++k) rres = fmaf(__shfl(xv, k, 64), sW[k * 64 + lane], rres);
        out[(size_t)r * 64 + lane] = nv + rres;
    }
}

extern "C" void kernel_launch(void* const* d_in, const int* in_sizes, int n_in,
                              void* d_out, int out_size, void* d_ws, size_t ws_size,
                              hipStream_t stream) {
    const float* x     = (const float*)d_in[0];
    const int*   ei    = (const int*)d_in[1];
    const float* eattr = (const float*)d_in[2];
    const int*   dist  = (const int*)d_in[3];
    const float* W_l   = (const float*)d_in[4];
    const float* b_l   = (const float*)d_in[5];
    const float* W_r   = (const float*)d_in[6];
    const float* b_r   = (const float*)d_in[7];
    const float* W_e   = (const float*)d_in[8];
    const float* att   = (const float*)d_in[9];
    const float* bias  = (const float*)d_in[10];
    const float* gamma = (const float*)d_in[11];
    const float* beta  = (const float*)d_in[12];
    const float* W_res = (const float*)d_in[13];
    const float* b_res = (const float*)d_in[14];
    const float* bph   = (const float*)d_in[15];

    int n  = in_sizes[0] / 64;
    int E_ = in_sizes[1] / 2;
    float* out = (float*)d_out;

    char* ws = (char*)d_ws;
    float* xl       = (float*)ws; ws += (size_t)n * 64 * 4;
    float* xr       = (float*)ws; ws += (size_t)n * 64 * 4;
    int2*  es       = (int2*)ws;  ws += (size_t)E_ * 8;
    int*   pos      = (int*)ws;   ws += (size_t)E_ * 4;
    int*   counts   = (int*)ws;   ws += (size_t)n * 4;
    int*   starts   = (int*)ws;   ws += (size_t)n * 4;
    int*   partials = (int*)ws;   ws += (size_t)1024 * 4;

    int nchunks = (n + SCAN_CHUNK - 1) / SCAN_CHUNK;

    hipMemsetAsync(counts, 0, (size_t)n * 4, stream);
    node_xf<<<2048, 256, 0, stream>>>(x, W_l, b_l, W_r, b_r, xl, xr, n);
    hist_kernel<<<(E_ + 255) / 256, 256, 0, stream>>>(ei, counts, pos, E_);
    scan1<<<nchunks, 256, 0, stream>>>(counts, starts, partials, n);
    scan2<<<1, 1024, 0, stream>>>(partials, nchunks);
    scan3<<<(n + 255) / 256, 256, 0, stream>>>(starts, partials, n);
    place_kernel<<<(E_ + 255) / 256, 256, 0, stream>>>(ei, starts, pos, es, E_);
    fused_gather<<<2048, 256, 0, stream>>>(starts, counts, es, eattr, dist, bph,
                                           W_e, att, xl, xr, x, W_res, b_res,
                                           bias, gamma, beta, out, n);
}

// Round 4
// 391.482 us; speedup vs baseline: 2.3756x; 1.6193x over previous
//
#include <hip/hip_runtime.h>
#include <math.h>

#define NEG_SLOPE 0.2f
#define LN_EPS 1e-5f
#define NEG_INF (-1e30f)

// ---------- node transform: xl = x@W_l+b_l ; xr = x@W_r+b_r ; xres = x@W_res+b_res ----
__global__ __launch_bounds__(256) void node_xf(
    const float* __restrict__ x,
    const float* __restrict__ W_l, const float* __restrict__ b_l,
    const float* __restrict__ W_r, const float* __restrict__ b_r,
    const float* __restrict__ W_res, const float* __restrict__ b_res,
    float* __restrict__ xl, float* __restrict__ xr, float* __restrict__ xres, int n) {
    __shared__ float sWl[4096];
    __shared__ float sWr[4096];
    __shared__ float sWs[4096];
    __shared__ float sx[256];
    for (int i = threadIdx.x; i < 4096; i += 256) {
        sWl[i] = W_l[i]; sWr[i] = W_r[i]; sWs[i] = W_res[i];
    }
    __syncthreads();
    int lane = threadIdx.x & 63;
    int w = threadIdx.x >> 6;
    float bl = b_l[lane], br = b_r[lane], bs = b_res[lane];
    for (int base = blockIdx.x * 4; base < n; base += gridDim.x * 4) {
        __syncthreads();
        int r = base + w;
        if (r < n) sx[threadIdx.x] = x[(size_t)r * 64 + lane];
        __syncthreads();
        if (r < n) {
            float al = bl, ar = br, as_ = bs;
            const float* xv = &sx[w * 64];
#pragma unroll
            for (int k = 0; k < 64; ++k) {
                float xk = xv[k];
                al = fmaf(xk, sWl[k * 64 + lane], al);
                ar = fmaf(xk, sWr[k * 64 + lane], ar);
                as_ = fmaf(xk, sWs[k * 64 + lane], as_);
            }
            xl[(size_t)r * 64 + lane] = al;
            xr[(size_t)r * 64 + lane] = ar;
            xres[(size_t)r * 64 + lane] = as_;
        }
    }
}

// ---------- histogram: counts[dst]++, pos[e] = old count ----------
__global__ void hist_kernel(const int* __restrict__ ei, int* __restrict__ counts,
                            int* __restrict__ pos, int E_) {
    int e = blockIdx.x * blockDim.x + threadIdx.x;
    if (e < E_) {
        int dst = ei[E_ + e];
        pos[e] = atomicAdd(&counts[dst], 1);
    }
}

// ---------- exclusive scan of counts -> starts (chunked) ----------
#define SCAN_CHUNK 1024
__global__ __launch_bounds__(256) void scan1(const int* __restrict__ counts,
                                             int* __restrict__ starts,
                                             int* __restrict__ partials, int n) {
    __shared__ int wsum[4];
    int base = blockIdx.x * SCAN_CHUNK;
    int t = threadIdx.x;
    int v[4]; int s = 0;
#pragma unroll
    for (int k = 0; k < 4; ++k) {
        int i = base + t * 4 + k;
        v[k] = (i < n) ? counts[i] : 0;
        s += v[k];
    }
    int lane = t & 63, w = t >> 6;
    int inc = s;
#pragma unroll
    for (int off = 1; off < 64; off <<= 1) {
        int u = __shfl_up(inc, off, 64);
        if (lane >= off) inc += u;
    }
    if (lane == 63) wsum[w] = inc;
    __syncthreads();
    int woff = 0;
    for (int i = 0; i < w; ++i) woff += wsum[i];
    int exc = woff + inc - s;
#pragma unroll
    for (int k = 0; k < 4; ++k) {
        int i = base + t * 4 + k;
        if (i < n) starts[i] = exc;
        exc += v[k];
    }
    if (t == 255) partials[blockIdx.x] = woff + inc;
}

__global__ __launch_bounds__(1024) void scan2(int* __restrict__ partials, int nchunks) {
    __shared__ int wsum[16];
    int t = threadIdx.x;
    int v = (t < nchunks) ? partials[t] : 0;
    int lane = t & 63, w = t >> 6;
    int inc = v;
#pragma unroll
    for (int off = 1; off < 64; off <<= 1) {
        int u = __shfl_up(inc, off, 64);
        if (lane >= off) inc += u;
    }
    if (lane == 63) wsum[w] = inc;
    __syncthreads();
    int woff = 0;
    for (int i = 0; i < w; ++i) woff += wsum[i];
    if (t < nchunks) partials[t] = woff + inc - v;
}

__global__ void scan3(int* __restrict__ starts, const int* __restrict__ partials, int n) {
    int i = blockIdx.x * blockDim.x + threadIdx.x;
    if (i < n) starts[i] += partials[i >> 10];
}

// ---------- place: es[slot] = (e, src) ----------
__global__ void place_kernel(const int* __restrict__ ei, const int* __restrict__ starts,
                             const int* __restrict__ pos, int2* __restrict__ es, int E_) {
    int e = blockIdx.x * blockDim.x + threadIdx.x;
    if (e < E_) {
        int dst = ei[E_ + e];
        int idx = starts[dst] + pos[e];
        es[idx] = make_int2(e, ei[e]);
    }
}

// ---------- fused: edge logits + deferred-max online softmax + gather + LN + res ------
// one wave per dst node; no LDS; W_e row for this lane held in 16 registers
__global__ __launch_bounds__(256) void fused_gather(
    const int* __restrict__ starts, const int* __restrict__ counts,
    const int2* __restrict__ es, const float* __restrict__ eattr,
    const int* __restrict__ dist, const float* __restrict__ bph,
    const float* __restrict__ W_e, const float* __restrict__ att,
    const float* __restrict__ xl, const float* __restrict__ xr,
    const float* __restrict__ xres, const float* __restrict__ bias,
    const float* __restrict__ gamma, const float* __restrict__ beta,
    float* __restrict__ out, int n) {
    int lane = threadIdx.x & 63;
    float attv = att[lane];
    float bi = bias[lane], g = gamma[lane], be = beta[lane];
    float w[16];
    float wsum = 0.0f;
#pragma unroll
    for (int k = 0; k < 16; ++k) { w[k] = W_e[k * 64 + lane]; wsum += w[k]; }

    int wid = (blockIdx.x * blockDim.x + threadIdx.x) >> 6;
    int nw = (gridDim.x * blockDim.x) >> 6;
    for (int r = wid; r < n; r += nw) {
        int s0 = starts[r];
        int cnt = counts[r];
        float mref = NEG_INF, den = 0.0f, acc = 0.0f;
        if (cnt > 0) {
            int hop = dist[r];
            hop = hop < 0 ? 0 : (hop > 3 ? 3 : hop);
            float hb = 0.1f * bph[hop];
            float base = fmaf(hb, wsum, xr[(size_t)r * 64 + lane]);
            int last = s0 + cnt - 1;
            int2 e_cur = es[s0];
            int2 e_nxt = es[cnt > 1 ? s0 + 1 : s0];
            float xl_cur = xl[(size_t)e_cur.y * 64 + lane];
            for (int i = 0; i < cnt; ++i) {
                int ecur = __builtin_amdgcn_readfirstlane(e_cur.x);
                float xlv = xl_cur;
                // rotate depth-2 pipeline (clamped, branch-free)
                e_cur = e_nxt;
                xl_cur = xl[(size_t)e_nxt.y * 64 + lane];
                int nx = s0 + i + 2; nx = nx > last ? last : nx;
                e_nxt = es[nx];
                // logit for this edge
                const float* ea = eattr + (size_t)ecur * 16;
                float m0 = xlv + base;
                float m1 = 0.0f;
#pragma unroll
                for (int k = 0; k < 16; k += 2) {
                    m0 = fmaf(ea[k], w[k], m0);
                    m1 = fmaf(ea[k + 1], w[k + 1], m1);
                }
                float m = m0 + m1;
                m = m > 0.0f ? m : NEG_SLOPE * m;
                float l = m * attv;
#pragma unroll
                for (int off = 1; off < 16; off <<= 1) l += __shfl_xor(l, off, 64);
                // deferred-max online softmax
                float d = l - mref;
                if (__any(d > 8.0f)) {
                    float mnew = fmaxf(mref, l);
                    float corr = __expf(mref - mnew);
                    den *= corr; acc *= corr; mref = mnew;
                    d = l - mref;
                }
                float ex = __expf(d);
                den += ex;
                acc = fmaf(ex, xlv, acc);
            }
        }
        float v = acc / (den + 1e-16f) + bi;
        // LayerNorm over 64 features
        float s = v;
#pragma unroll
        for (int off = 1; off < 64; off <<= 1) s += __shfl_xor(s, off, 64);
        float mu = s * (1.0f / 64.0f);
        float dd = v - mu;
        float q = dd * dd;
#pragma unroll
        for (int off = 1; off < 64; off <<= 1) q += __shfl_xor(q, off, 64);
        float var = q * (1.0f / 64.0f);
        float nv = dd * rsqrtf(var + LN_EPS) * g + be;
        out[(size_t)r * 64 + lane] = nv + xres[(size_t)r * 64 + lane];
    }
}

extern "C" void kernel_launch(void* const* d_in, const int* in_sizes, int n_in,
                              void* d_out, int out_size, void* d_ws, size_t ws_size,
                              hipStream_t stream) {
    const float* x     = (const float*)d_in[0];
    const int*   ei    = (const int*)d_in[1];
    const float* eattr = (const float*)d_in[2];
    const int*   dist  = (const int*)d_in[3];
    const float* W_l   = (const float*)d_in[4];
    const float* b_l   = (const float*)d_in[5];
    const float* W_r   = (const float*)d_in[6];
    const float* b_r   = (const float*)d_in[7];
    const float* W_e   = (const float*)d_in[8];
    const float* att   = (const float*)d_in[9];
    const float* bias  = (const float*)d_in[10];
    const float* gamma = (const float*)d_in[11];
    const float* beta  = (const float*)d_in[12];
    const float* W_res = (const float*)d_in[13];
    const float* b_res = (const float*)d_in[14];
    const float* bph   = (const float*)d_in[15];

    int n  = in_sizes[0] / 64;
    int E_ = in_sizes[1] / 2;
    float* out = (float*)d_out;

    char* ws = (char*)d_ws;
    float* xl       = (float*)ws; ws += (size_t)n * 64 * 4;
    float* xr       = (float*)ws; ws += (size_t)n * 64 * 4;
    float* xres     = (float*)ws; ws += (size_t)n * 64 * 4;
    int2*  es       = (int2*)ws;  ws += (size_t)E_ * 8;
    int*   pos      = (int*)ws;   ws += (size_t)E_ * 4;
    int*   counts   = (int*)ws;   ws += (size_t)n * 4;
    int*   starts   = (int*)ws;   ws += (size_t)n * 4;
    int*   partials = (int*)ws;   ws += (size_t)1024 * 4;

    int nchunks = (n + SCAN_CHUNK - 1) / SCAN_CHUNK;

    hipMemsetAsync(counts, 0, (size_t)n * 4, stream);
    node_xf<<<2048, 256, 0, stream>>>(x, W_l, b_l, W_r, b_r, W_res, b_res, xl, xr, xres, n);
    hist_kernel<<<(E_ + 255) / 256, 256, 0, stream>>>(ei, counts, pos, E_);
    scan1<<<nchunks, 256, 0, stream>>>(counts, starts, partials, n);
    scan2<<<1, 1024, 0, stream>>>(partials, nchunks);
    scan3<<<(n + 255) / 256, 256, 0, stream>>>(starts, partials, n);
    place_kernel<<<(E_ + 255) / 256, 256, 0, stream>>>(ei, starts, pos, es, E_);
    fused_gather<<<2048, 256, 0, stream>>>(starts, counts, es, eattr, dist, bph,
                                           W_e, att, xl, xr, xres,
                                           bias, gamma, beta, out, n);
}

// Round 5
// 385.758 us; speedup vs baseline: 2.4108x; 1.0148x over previous
//
#include <hip/hip_runtime.h>
#include <math.h>

#define NEG_SLOPE 0.2f
#define LN_EPS 1e-5f
#define NEG_INF (-1e30f)

// DPP-based add: x += x permuted by CTRL (within 16-lane rows)
template <int CTRL>
__device__ __forceinline__ float dpp_add(float x) {
    int s = __builtin_amdgcn_update_dpp(0, __float_as_int(x), CTRL, 0xF, 0xF, true);
    return x + __int_as_float(s);
}
// full 16-lane row sum: quad swap1, quad swap2, row_ror4, row_ror8
__device__ __forceinline__ float row16_sum(float x) {
    x = dpp_add<0xB1>(x);   // quad_perm [1,0,3,2]
    x = dpp_add<0x4E>(x);   // quad_perm [2,3,0,1]
    x = dpp_add<0x124>(x);  // row_ror:4
    x = dpp_add<0x128>(x);  // row_ror:8
    return x;
}

// ---------- prep: node transforms (xl,xr,xres) + dst histogram ----------
__global__ __launch_bounds__(256) void prep(
    const float* __restrict__ x,
    const float* __restrict__ W_l, const float* __restrict__ b_l,
    const float* __restrict__ W_r, const float* __restrict__ b_r,
    const float* __restrict__ W_res, const float* __restrict__ b_res,
    float* __restrict__ xl, float* __restrict__ xr, float* __restrict__ xres,
    const int* __restrict__ ei, int* __restrict__ counts, int n, int E_) {
    __shared__ float sWl[4096];
    __shared__ float sWr[4096];
    __shared__ float sWs[4096];
    __shared__ float sx[256];
    for (int i = threadIdx.x; i < 4096; i += 256) {
        sWl[i] = W_l[i]; sWr[i] = W_r[i]; sWs[i] = W_res[i];
    }
    __syncthreads();
    int lane = threadIdx.x & 63;
    int w = threadIdx.x >> 6;
    float bl = b_l[lane], br = b_r[lane], bs = b_res[lane];
    for (int base = blockIdx.x * 4; base < n; base += gridDim.x * 4) {
        __syncthreads();
        int r = base + w;
        if (r < n) sx[threadIdx.x] = x[(size_t)r * 64 + lane];
        __syncthreads();
        if (r < n) {
            float al = bl, ar = br, as_ = bs;
            const float* xv = &sx[w * 64];
#pragma unroll
            for (int k = 0; k < 64; ++k) {
                float xk = xv[k];
                al = fmaf(xk, sWl[k * 64 + lane], al);
                ar = fmaf(xk, sWr[k * 64 + lane], ar);
                as_ = fmaf(xk, sWs[k * 64 + lane], as_);
            }
            xl[(size_t)r * 64 + lane] = al;
            xr[(size_t)r * 64 + lane] = ar;
            xres[(size_t)r * 64 + lane] = as_;
        }
    }
    // histogram phase (independent of node phase)
    const int* di = ei + E_;
    for (int e = blockIdx.x * 256 + threadIdx.x; e < E_; e += gridDim.x * 256)
        atomicAdd(&counts[di[e]], 1);
}

// ---------- exclusive scan of counts -> starts (chunked) ----------
#define SCAN_CHUNK 1024
__global__ __launch_bounds__(256) void scan1(const int* __restrict__ counts,
                                             int* __restrict__ starts,
                                             int* __restrict__ partials, int n) {
    __shared__ int wsum[4];
    int base = blockIdx.x * SCAN_CHUNK;
    int t = threadIdx.x;
    int v[4]; int s = 0;
#pragma unroll
    for (int k = 0; k < 4; ++k) {
        int i = base + t * 4 + k;
        v[k] = (i < n) ? counts[i] : 0;
        s += v[k];
    }
    int lane = t & 63, w = t >> 6;
    int inc = s;
#pragma unroll
    for (int off = 1; off < 64; off <<= 1) {
        int u = __shfl_up(inc, off, 64);
        if (lane >= off) inc += u;
    }
    if (lane == 63) wsum[w] = inc;
    __syncthreads();
    int woff = 0;
    for (int i = 0; i < w; ++i) woff += wsum[i];
    int exc = woff + inc - s;
#pragma unroll
    for (int k = 0; k < 4; ++k) {
        int i = base + t * 4 + k;
        if (i < n) starts[i] = exc;
        exc += v[k];
    }
    if (t == 255) partials[blockIdx.x] = woff + inc;
}

__global__ __launch_bounds__(1024) void scan2(int* __restrict__ partials, int nchunks) {
    __shared__ int wsum[16];
    int t = threadIdx.x;
    int v = (t < nchunks) ? partials[t] : 0;
    int lane = t & 63, w = t >> 6;
    int inc = v;
#pragma unroll
    for (int off = 1; off < 64; off <<= 1) {
        int u = __shfl_up(inc, off, 64);
        if (lane >= off) inc += u;
    }
    if (lane == 63) wsum[w] = inc;
    __syncthreads();
    int woff = 0;
    for (int i = 0; i < w; ++i) woff += wsum[i];
    if (t < nchunks) partials[t] = woff + inc - v;
}

__global__ void scan3(int* __restrict__ starts, const int* __restrict__ partials, int n) {
    int i = blockIdx.x * blockDim.x + threadIdx.x;
    if (i < n) starts[i] += partials[i >> 10];
}

// ---------- place: es[starts[dst] + cursor[dst]++] = (e, src) ----------
__global__ void place_kernel(const int* __restrict__ ei, const int* __restrict__ starts,
                             int* __restrict__ cursor, int2* __restrict__ es, int E_) {
    int e = blockIdx.x * blockDim.x + threadIdx.x;
    if (e < E_) {
        int dst = ei[E_ + e];
        int idx = starts[dst] + atomicAdd(&cursor[dst], 1);
        es[idx] = make_int2(e, ei[e]);
    }
}

// ---------- fused: edge logits + deferred-max online softmax + gather + LN + res ------
__global__ __launch_bounds__(256) void fused_gather(
    const int* __restrict__ starts, const int* __restrict__ counts,
    const int2* __restrict__ es, const float* __restrict__ eattr,
    const int* __restrict__ dist, const float* __restrict__ bph,
    const float* __restrict__ W_e, const float* __restrict__ att,
    const float* __restrict__ xl, const float* __restrict__ xr,
    const float* __restrict__ xres, const float* __restrict__ bias,
    const float* __restrict__ gamma, const float* __restrict__ beta,
    float* __restrict__ out, int n) {
    int lane = threadIdx.x & 63;
    float attv = att[lane];
    float bi = bias[lane], g = gamma[lane], be = beta[lane];
    float w[16];
    float wsum = 0.0f;
#pragma unroll
    for (int k = 0; k < 16; ++k) { w[k] = W_e[k * 64 + lane]; wsum += w[k]; }

    int wid = (blockIdx.x * blockDim.x + threadIdx.x) >> 6;
    int nw = (gridDim.x * blockDim.x) >> 6;
    for (int r = wid; r < n; r += nw) {
        int s0 = starts[r];
        int cnt = counts[r];
        float mref = NEG_INF, den = 0.0f, acc = 0.0f;
        if (cnt > 0) {
            int hop = dist[r];
            hop = hop < 0 ? 0 : (hop > 3 ? 3 : hop);
            float hb = 0.1f * bph[hop];
            float base = fmaf(hb, wsum, xr[((unsigned)r << 6) | lane]);
            int last = s0 + cnt - 1;
            // depth-3 pipeline
            int iB = s0 + 1 > last ? last : s0 + 1;
            int iC = s0 + 2 > last ? last : s0 + 2;
            int2 eA = es[s0];
            int2 eB = es[iB];
            int2 eC = es[iC];
            float xA = xl[((unsigned)eA.y << 6) | lane];
            float xB = xl[((unsigned)eB.y << 6) | lane];
            for (int i = 0; i < cnt; ++i) {
                int ecur = __builtin_amdgcn_readfirstlane(eA.x);
                float xlv = xA;
                // rotate pipeline
                eA = eB; xA = xB;
                eB = eC; xB = xl[((unsigned)eC.y << 6) | lane];
                int nx = s0 + i + 3; nx = nx > last ? last : nx;
                eC = es[nx];
                // logit
                const float* ea = eattr + (size_t)ecur * 16;
                float m0 = xlv + base;
                float m1 = 0.0f;
#pragma unroll
                for (int k = 0; k < 16; k += 2) {
                    m0 = fmaf(ea[k], w[k], m0);
                    m1 = fmaf(ea[k + 1], w[k + 1], m1);
                }
                float m = m0 + m1;
                m = fmaxf(m, NEG_SLOPE * m);  // leaky relu (slope<1)
                float l = row16_sum(m * attv);
                // deferred-max online softmax
                float d = l - mref;
                if (__any(d > 8.0f)) {
                    float mnew = fmaxf(mref, l);
                    float corr = __expf(mref - mnew);
                    den *= corr; acc *= corr; mref = mnew;
                    d = l - mref;
                }
                float ex = __expf(d);
                den += ex;
                acc = fmaf(ex, xlv, acc);
            }
        }
        float v = acc / (den + 1e-16f) + bi;
        // LayerNorm over 64 features
        float s = v;
#pragma unroll
        for (int off = 1; off < 64; off <<= 1) s += __shfl_xor(s, off, 64);
        float mu = s * (1.0f / 64.0f);
        float dd = v - mu;
        float q = dd * dd;
#pragma unroll
        for (int off = 1; off < 64; off <<= 1) q += __shfl_xor(q, off, 64);
        float var = q * (1.0f / 64.0f);
        float nv = dd * rsqrtf(var + LN_EPS) * g + be;
        out[((unsigned)r << 6) | lane] = nv + xres[((unsigned)r << 6) | lane];
    }
}

extern "C" void kernel_launch(void* const* d_in, const int* in_sizes, int n_in,
                              void* d_out, int out_size, void* d_ws, size_t ws_size,
                              hipStream_t stream) {
    const float* x     = (const float*)d_in[0];
    const int*   ei    = (const int*)d_in[1];
    const float* eattr = (const float*)d_in[2];
    const int*   dist  = (const int*)d_in[3];
    const float* W_l   = (const float*)d_in[4];
    const float* b_l   = (const float*)d_in[5];
    const float* W_r   = (const float*)d_in[6];
    const float* b_r   = (const float*)d_in[7];
    const float* W_e   = (const float*)d_in[8];
    const float* att   = (const float*)d_in[9];
    const float* bias  = (const float*)d_in[10];
    const float* gamma = (const float*)d_in[11];
    const float* beta  = (const float*)d_in[12];
    const float* W_res = (const float*)d_in[13];
    const float* b_res = (const float*)d_in[14];
    const float* bph   = (const float*)d_in[15];

    int n  = in_sizes[0] / 64;
    int E_ = in_sizes[1] / 2;
    float* out = (float*)d_out;

    char* ws = (char*)d_ws;
    float* xl       = (float*)ws; ws += (size_t)n * 64 * 4;
    float* xr       = (float*)ws; ws += (size_t)n * 64 * 4;
    float* xres     = (float*)ws; ws += (size_t)n * 64 * 4;
    int2*  es       = (int2*)ws;  ws += (size_t)E_ * 8;
    int*   counts   = (int*)ws;   ws += (size_t)n * 4;
    int*   cursor   = (int*)ws;   ws += (size_t)n * 4;
    int*   starts   = (int*)ws;   ws += (size_t)n * 4;
    int*   partials = (int*)ws;   ws += (size_t)1024 * 4;

    int nchunks = (n + SCAN_CHUNK - 1) / SCAN_CHUNK;

    hipMemsetAsync(counts, 0, (size_t)n * 2 * 4, stream);  // counts + cursor
    prep<<<2048, 256, 0, stream>>>(x, W_l, b_l, W_r, b_r, W_res, b_res,
                                   xl, xr, xres, ei, counts, n, E_);
    scan1<<<nchunks, 256, 0, stream>>>(counts, starts, partials, n);
    scan2<<<1, 1024, 0, stream>>>(partials, nchunks);
    scan3<<<(n + 255) / 256, 256, 0, stream>>>(starts, partials, n);
    place_kernel<<<(E_ + 255) / 256, 256, 0, stream>>>(ei, starts, cursor, es, E_);
    fused_gather<<<2048, 256, 0, stream>>>(starts, counts, es, eattr, dist, bph,
                                           W_e, att, xl, xr, xres,
                                           bias, gamma, beta, out, n);
}